// Round 8
// baseline (15.862 us; speedup 1.0000x reference)
//
#include <hip/hip_runtime.h>

#define NJ 22
#define CAM_DIM 3

// Gram-Schmidt 6D->3x3 (ROMP convention). r[] holds b1,b2,b3 as rows of storage;
// both sides of every dot use the same layout, so orientation is consistent.
__device__ __forceinline__ void rot6(const float* __restrict__ p, float r[9]) {
    float a1x = p[0], a2x = p[1];
    float a1y = p[2], a2y = p[3];
    float a1z = p[4], a2z = p[5];
    float n1 = sqrtf(a1x*a1x + a1y*a1y + a1z*a1z);
    float b1x = a1x/n1, b1y = a1y/n1, b1z = a1z/n1;
    float d = b1x*a2x + b1y*a2y + b1z*a2z;
    float px = a2x - d*b1x, py = a2y - d*b1y, pz = a2z - d*b1z;
    float np = sqrtf(px*px + py*py + pz*pz);
    float b2x = px/np, b2y = py/np, b2z = pz/np;
    r[0]=b1x; r[1]=b1y; r[2]=b1z;
    r[3]=b2x; r[4]=b2y; r[5]=b2z;
    r[6]=b1y*b2z - b1z*b2y;
    r[7]=b1z*b2x - b1x*b2z;
    r[8]=b1x*b2y - b1y*b2x;
}

// ONE kernel, block i = row i. No prologue, no LDS tiles, one barrier.
// Gate: 4 consecutive j's per thread per chunk (contiguous float4 stores).
// Pose: wave-cooperative (lanes 0..21 = joints, ri+rj recomputed per hit).
// Argmax: deterministic packed-u64 shuffle reduction (no atomics).
__global__ __launch_bounds__(256) void mega_kernel(
        const float* __restrict__ params,
        const int* __restrict__ batch_ids,
        const int* __restrict__ czyx,
        const float* __restrict__ ts,
        float* __restrict__ out,
        float* __restrict__ nms,
        int n, int param_dim) {
    __shared__ unsigned long long s_red[4];

    const int i    = blockIdx.x;
    const int tid  = threadIdx.x;
    const int lane = tid & 63;
    const int wid  = tid >> 6;

    const int bi  = batch_ids[i];
    const int ciy = czyx[3*i + 1];
    const int cix = czyx[3*i + 2];
    float* row = out + (size_t)i * n;

    // packed best = (score_bits << 32) | ~j ; scores >= 0 so bit-compare works.
    unsigned long long best = 0ull;

    for (int base = 0; base < n; base += blockDim.x * 4) {
        int j0 = base + tid * 4;
        if (j0 >= n) continue;   // uniform per wave when n % 1024 == 0

        int okmask = 0;
        if (j0 + 3 < n) {
            int4 b4 = *reinterpret_cast<const int4*>(batch_ids + j0);
            const int4* cz = reinterpret_cast<const int4*>(czyx + 3*j0);
            int4 c0 = cz[0], c1 = cz[1], c2 = cz[2];
            int by[4] = {b4.x, b4.y, b4.z, b4.w};
            int yy[4] = {c0.y, c1.x, c1.w, c2.z};
            int xx[4] = {c0.z, c1.y, c2.x, c2.w};
            #pragma unroll
            for (int u = 0; u < 4; ++u) {
                int dy = yy[u] - ciy, dx = xx[u] - cix;
                if ((by[u] == bi) && (dy*dy + dx*dx <= 25)) okmask |= 1 << u;
            }
        } else {
            for (int u = 0; u < 4 && j0 + u < n; ++u) {
                int j = j0 + u;
                int dy = czyx[3*j + 1] - ciy, dx = czyx[3*j + 2] - cix;
                if ((batch_ids[j] == bi) && (dy*dy + dx*dx <= 25)) okmask |= 1 << u;
            }
        }

        // diagonal passes exactly in the reference (c_dist=0, pose_dist=0)
        int passmask = 0;
        int du = i - j0;
        if (du >= 0 && du < 4) {
            passmask |=  (1 << du);
            okmask   &= ~(1 << du);
        }

        // wave-cooperative pose evaluation of the rare gate hits
        for (;;) {
            unsigned long long pend = __ballot(okmask != 0);
            if (pend == 0ull) break;
            int leader = __ffsll((long long)pend) - 1;
            int lok = __shfl(okmask, leader);
            int u   = __ffs(lok) - 1;
            int j   = __shfl(j0, leader) + u;

            float val = 0.0f;
            if (lane < NJ) {
                const float* pi_ = params + (size_t)i * param_dim + CAM_DIM + lane * 6;
                const float* pj_ = params + (size_t)j * param_dim + CAM_DIM + lane * 6;
                float ri[9], rj[9];
                rot6(pi_, ri);
                rot6(pj_, rj);
                float g = 0.0f, ni = 0.0f, nj = 0.0f;
                #pragma unroll
                for (int a = 0; a < 9; ++a) {
                    g  += ri[a]*rj[a];
                    ni += ri[a]*ri[a];
                    nj += rj[a]*rj[a];
                }
                val = sqrtf(fmaxf(ni + nj - 2.0f*g, 0.0f));
            }
            #pragma unroll
            for (int off = 16; off > 0; off >>= 1) val += __shfl_down(val, off, 32);
            float pd = __shfl(val, 0) * (1.0f / 22.0f);

            if (lane == leader) {
                okmask &= ~(1 << u);
                if (pd < 2.5f) passmask |= 1 << u;
            }
        }

        // dense contiguous store + fold this chunk into the thread's argmax best
        float sc[4];
        #pragma unroll
        for (int u = 0; u < 4; ++u)
            sc[u] = ((passmask >> u) & 1) ? ts[j0 + u] : 0.0f;

        // zero-score contribution at this chunk's smallest j (argmax-of-zeros = j 0)
        unsigned long long cand = (unsigned int)(~(unsigned int)j0);
        if (cand > best) best = cand;
        #pragma unroll
        for (int u = 0; u < 4; ++u) {
            if ((passmask >> u) & 1) {
                unsigned long long p =
                    ((unsigned long long)__float_as_uint(sc[u]) << 32) |
                    (unsigned int)(~(unsigned int)(j0 + u));
                if (p > best) best = p;
            }
        }

        if (j0 + 3 < n) {
            *reinterpret_cast<float4*>(row + j0) = make_float4(sc[0], sc[1], sc[2], sc[3]);
        } else {
            for (int u = 0; u < 4 && j0 + u < n; ++u) row[j0 + u] = sc[u];
        }
    }

    // wave reduce packed best, then block reduce via 4-entry LDS
    #pragma unroll
    for (int off = 32; off > 0; off >>= 1) {
        unsigned long long o = __shfl_xor(best, off);
        if (o > best) best = o;
    }
    if (lane == 0) s_red[wid] = best;
    __syncthreads();
    if (tid == 0) {
        unsigned long long b = s_red[0];
        #pragma unroll
        for (int w = 1; w < 4; ++w) if (s_red[w] > b) b = s_red[w];
        unsigned int jwin = ~(unsigned int)(b & 0xFFFFFFFFull);
        nms[i] = (jwin == (unsigned int)i) ? 1.0f : 0.0f;
    }
}

extern "C" void kernel_launch(void* const* d_in, const int* in_sizes, int n_in,
                              void* d_out, int out_size, void* d_ws, size_t ws_size,
                              hipStream_t stream) {
    const float* params = (const float*)d_in[0];
    const int*   batch  = (const int*)d_in[1];
    const int*   czyx   = (const int*)d_in[2];
    const float* ts     = (const float*)d_in[3];

    const int n = in_sizes[1];                 // N = 2048
    const int param_dim = in_sizes[0] / n;     // 145

    float* out = (float*)d_out;        // score_map [n*n]
    float* nms = out + (size_t)n * n;  // nms_inds [n] as 0/1 floats

    mega_kernel<<<n, 256, 0, stream>>>(params, batch, czyx, ts, out, nms, n, param_dim);
}